// Round 10
// baseline (254.322 us; speedup 1.0000x reference)
//
#include <hip/hip_runtime.h>

// B=32, S=127, new_seq=128, D=768, H=12, HD=64
#define NB 32
#define NS 128
#define SD 127
#define ND 768
#define NH 12
#define HD 64
#define GRID 256

__device__ inline float wredSum(float v){
  #pragma unroll
  for (int off=32; off>0; off>>=1) v += __shfl_xor(v, off);
  return v;
}
__device__ inline float wredMax(float v){
  #pragma unroll
  for (int off=32; off>0; off>>=1) v = fmaxf(v, __shfl_xor(v, off));
  return v;
}

// Software grid barrier. GRID=256 <= #CUs and 24 KB LDS / 96 VGPR -> >=1
// block/CU resident: deadlock-impossible. Arrival is ONE device-scope RMW per
// block; the wait is LOAD-based polling (sc1 load from the coherence point) --
// R9's RMW-polling caused cross-XCD cacheline ping-pong (~43 us/barrier).
__device__ inline void gridbar(int* cnt){
  __syncthreads();
  if (threadIdx.x == 0){
    __threadfence();   // release: drain this block's writes to device scope
    __hip_atomic_fetch_add(cnt, 1, __ATOMIC_RELEASE, __HIP_MEMORY_SCOPE_AGENT);
    while (__hip_atomic_load(cnt, __ATOMIC_ACQUIRE, __HIP_MEMORY_SCOPE_AGENT) < GRID)
      __builtin_amdgcn_s_sleep(8);
    __threadfence();   // acquire: invalidate stale lines
  }
  __syncthreads();
}

__global__ __launch_bounds__(256)
void mega(const float* __restrict__ desc, const float* __restrict__ nv,
          const float* __restrict__ Wk, const float* __restrict__ bk,
          const float* __restrict__ Wv, const float* __restrict__ bv,
          const float* __restrict__ Wa,
          int* __restrict__ bar, float* __restrict__ uk, float* __restrict__ bkdot,
          float* __restrict__ lk, float* __restrict__ ei,
          float* __restrict__ m_part, float* __restrict__ out){
  __shared__ __align__(16) float S[6144];            // 24 KB, aliased per phase
  int blk = blockIdx.x, t = threadIdx.x, wave = t>>6, lane = t&63;

  // ---------------- Phase A: fold uk (blk<144), bkdot, ei (all blocks) -------
  if (blk < 144){
    float (*red)[64] = (float(*)[64])S;
    int h = blk/12, cb = blk%12;
    int c0 = t & 63, dg = t >> 6;
    const float* base = Wk + (size_t)(h*HD + dg*16)*ND + cb*64 + c0;
    float acc = 0.f;
    #pragma unroll
    for (int i=0;i<16;++i) acc += base[(size_t)i*ND] * Wa[64 + dg*16 + i];
    red[dg][c0] = acc;
    __syncthreads();
    if (dg==0) uk[h*ND + cb*64 + c0] = red[0][c0]+red[1][c0]+red[2][c0]+red[3][c0];
  }
  if (blk == 144 && t < NH){
    float a = 0.f;
    for (int d=0; d<64; ++d) a += bk[t*HD+d]*Wa[64+d];
    bkdot[t] = a;
  }
  {
    float wea = Wa[128 + lane];
    for (int task = blk; task < NB*SD; task += GRID){
      int b = task / SD, s = task % SD;
      const float* row = desc + (size_t)task * ND;
      #pragma unroll
      for (int hh=0; hh<3; ++hh){
        int h = wave + hh*4;
        float v = row[h*HD + lane] * wea;
        v = wredSum(v);
        if (lane==0) ei[(size_t)(b*NH + h)*NS + s] = v;
      }
    }
  }
  gridbar(bar + 0);

  // ---------------- Phase B: lk rows; uk kept in 36 regs/lane ----------------
  {
    float ukr[3][12], bkd[3];
    #pragma unroll
    for (int hh=0; hh<3; ++hh){
      int h = wave*3 + hh;
      bkd[hh] = bkdot[h];
      #pragma unroll
      for (int k=0;k<12;++k) ukr[hh][k] = uk[h*ND + lane + 64*k];
    }
    for (int it = blk; it < 1024; it += GRID){       // 4 nv rows per iter
      int j0 = it*4;                                 // same b for all 4 rows
      const float4* src = (const float4*)(nv + (size_t)j0*ND);
      ((float4*)S)[t]     = src[t];
      ((float4*)S)[t+256] = src[t+256];
      ((float4*)S)[t+512] = src[t+512];
      __syncthreads();
      float acc[12];
      #pragma unroll
      for (int rr=0; rr<4; ++rr){
        #pragma unroll
        for (int hh=0; hh<3; ++hh){
          float a = 0.f;
          #pragma unroll
          for (int k=0;k<12;++k) a += S[rr*ND + lane + 64*k]*ukr[hh][k];
          acc[rr*3+hh] = a;
        }
      }
      #pragma unroll
      for (int i=0;i<12;++i) acc[i] = wredSum(acc[i]);
      if (lane == 0){
        int b = j0 >> 7, jb = j0 & 127;
        #pragma unroll
        for (int rr=0; rr<4; ++rr){
          #pragma unroll
          for (int hh=0; hh<3; ++hh){
            int h = wave*3 + hh;
            lk[(size_t)(b*NH + h)*NS + jb + rr] = acc[rr*3+hh] + bkd[hh];
          }
        }
      }
      __syncthreads();
    }
  }
  gridbar(bar + 1);

  // ------- Phase C: per (b,jg): softmax -> m partials + attn row writes ------
  {
    int b = blk >> 3, jg = blk & 7;
    float* slk = S;                                // 1536
    float* sei = S + 1536;                         // 1536
    float (*wf)[NS] = (float(*)[NS])(S + 3072);    // 24*128
    for (int i=t; i<1536; i+=256) slk[i] = lk[(size_t)b*1536 + i];
    for (int i=t; i<1536; i+=256) sei[i] = ei[(size_t)b*1536 + i];
    __syncthreads();
    #pragma unroll
    for (int rr=0; rr<6; ++rr){
      int r = wave*6 + rr;
      int h = r >> 1, which = r & 1;
      const float* eirow = (which==0) ? (sei + (h%6)*NS) : (sei + h*NS);
      float g = (which==0) ? 1.f : (h>=6 ? 1.f : 0.f);
      float x0 = (lane>=1) ? slk[h*NS+lane] + g*eirow[lane-1] : -3.0e38f;
      float x1 = slk[h*NS+lane+64] + g*eirow[lane+63];
      float mm = wredMax(fmaxf(x0,x1));
      float e0 = (lane>=1) ? __expf(x0-mm) : 0.f;  // col 0 masked -> exactly 0
      float e1 = __expf(x1-mm);
      float s  = wredSum(e0+e1);
      float inv = 1.f/s;
      wf[r][lane]    = e0*inv;
      wf[r][lane+64] = e1*inv;
    }
    __syncthreads();
    if (t < 192){
      const float4* nvb = (const float4*)(nv + ((size_t)b*NS + jg*16)*ND);
      float4 acc[24];
      #pragma unroll
      for (int r=0;r<24;++r) acc[r] = make_float4(0.f,0.f,0.f,0.f);
      #pragma unroll 2
      for (int jj=0; jj<16; ++jj){
        float4 x = nvb[jj*192 + t];
        int j = jg*16 + jj;
        #pragma unroll
        for (int r=0;r<24;++r){
          float wr = wf[r][j];
          acc[r].x += wr*x.x; acc[r].y += wr*x.y;
          acc[r].z += wr*x.z; acc[r].w += wr*x.w;
        }
      }
      #pragma unroll
      for (int r=0;r<24;++r)
        ((float4*)(m_part + ((size_t)(b*24 + r)*8 + jg)*ND))[t] = acc[r];
    }
    // attn rows [jg*16, jg*16+16) for all 12 heads: 6144 float4
    float* abase = out + (size_t)NB*NS*ND + (size_t)(b*NH)*NS*NS;
    for (int idx=t; idx<6144; idx+=256){
      int h = idx >> 9;
      int rem = idx & 511;
      int il = rem >> 5, q = rem & 31;
      int i = jg*16 + il;
      const float* srcw = (i==0) ? wf[h*2] : wf[h*2+1];
      float4 v = { srcw[q*4], srcw[q*4+1], srcw[q*4+2], srcw[q*4+3] };
      ((float4*)(abase + (size_t)h*NS*NS))[i*32 + q] = v;
    }
  }
  gridbar(bar + 2);

  // ------- Phase D: per (b,h): sum partials -> V-proj -> basis write ---------
  for (int task = blk; task < NB*NH; task += GRID){
    int b = task / NH, h = task % NH;
    float* msum0 = S;            // 768
    float* msum1 = S + ND;       // 768
    float* cvec  = S + 2*ND;     // 128
    for (int i=t; i<2*ND; i+=256){
      int rl = (i >= ND);
      int c  = i - rl*ND;
      const float* mp = m_part + ((size_t)(b*24 + h*2 + rl)*8)*ND + c;
      float s = 0.f;
      #pragma unroll
      for (int g8=0; g8<8; ++g8) s += mp[(size_t)g8*ND];
      (rl ? msum1 : msum0)[c] = s;
    }
    __syncthreads();
    #pragma unroll
    for (int dd=0; dd<16; ++dd){
      int d = wave*16 + dd;
      const float* wvr = Wv + (size_t)(h*HD + d)*ND;
      float p0=0.f, p1=0.f;
      #pragma unroll
      for (int k=0; k<12; ++k){
        float wv = wvr[lane + 64*k];
        p0 += wv*msum0[lane + 64*k];
        p1 += wv*msum1[lane + 64*k];
      }
      p0 = wredSum(p0); p1 = wredSum(p1);
      if (lane==0){
        float bb = bv[h*HD + d];
        cvec[d]    = p0 + bb;
        cvec[64+d] = p1 + bb;
      }
    }
    __syncthreads();
    float* bo = out + (size_t)b*NS*ND + h*HD;
    for (int idx=t; idx<2048; idx+=256){
      int i = idx>>4, q = idx&15;
      const float* srcc = (i==0) ? cvec : cvec+64;
      float4 v = { srcc[q*4], srcc[q*4+1], srcc[q*4+2], srcc[q*4+3] };
      *(float4*)(bo + (size_t)i*ND + q*4) = v;
    }
    __syncthreads();
  }
}

extern "C" void kernel_launch(void* const* d_in, const int* in_sizes, int n_in,
                              void* d_out, int out_size, void* d_ws, size_t ws_size,
                              hipStream_t stream) {
  const float* desc = (const float*)d_in[0];
  const float* nv   = (const float*)d_in[1];
  // d_in[2]=Wq, d_in[3]=bq: unused (softmax shift-invariance)
  const float* Wk   = (const float*)d_in[4];
  const float* bk   = (const float*)d_in[5];
  const float* Wv   = (const float*)d_in[6];
  const float* bv   = (const float*)d_in[7];
  const float* Wa   = (const float*)d_in[8];
  // d_in[9]=ba: unused (constant shift)
  float* out  = (float*)d_out;
  float* base = (float*)d_ws;

  int*   bar    = (int*)d_ws;        // 16 ints reserved (64 B)
  float* uk     = base + 16;         // 9216
  float* bkdot  = base + 9232;       // 16
  float* lkbuf  = base + 9248;       // 49152
  float* eibuf  = base + 58400;      // 49152
  float* m_part = base + 107552;     // 4718592

  hipMemsetAsync(d_ws, 0, 64, stream);   // zero barrier counters (graph-legal)
  mega<<<GRID, 256, 0, stream>>>(desc, nv, Wk, bk, Wv, bv, Wa,
                                 bar, uk, bkdot, lkbuf, eibuf, m_part, out);
}

// Round 11
// 138.692 us; speedup vs baseline: 1.8337x; 1.8337x over previous
//
#include <hip/hip_runtime.h>

// B=32, S=127, new_seq=128, D=768, H=12, HD=64
#define NB 32
#define NS 128
#define SD 127
#define ND 768
#define NH 12
#define HD 64

__device__ inline float wredSum(float v){
  #pragma unroll
  for (int off=32; off>0; off>>=1) v += __shfl_xor(v, off);
  return v;
}
__device__ inline float wredMax(float v){
  #pragma unroll
  for (int off=32; off>0; off>>=1) v = fmaxf(v, __shfl_xor(v, off));
  return v;
}

// N0: fold uk (blk<144) + bkdot (blk 0) + ei rows (blk>=144)
__global__ __launch_bounds__(256)
void fold_ei(const float* __restrict__ Wk, const float* __restrict__ bk,
             const float* __restrict__ desc, const float* __restrict__ Wa,
             float* __restrict__ uk, float* __restrict__ bkdot,
             float* __restrict__ ei){
  int blk = blockIdx.x, t = threadIdx.x;
  int wave = t >> 6, lane = t & 63;
  if (blk < 144){
    __shared__ float red[4][64];
    int h = blk/12, cb = blk%12;
    int c0 = t & 63, dg = t >> 6;
    const float* base = Wk + (size_t)(h*HD + dg*16)*ND + cb*64 + c0;
    float acc = 0.f;
    #pragma unroll
    for (int i=0;i<16;++i) acc += base[(size_t)i*ND] * Wa[64 + dg*16 + i];
    red[dg][c0] = acc;
    __syncthreads();
    if (dg==0) uk[h*ND + cb*64 + c0] = red[0][c0]+red[1][c0]+red[2][c0]+red[3][c0];
    if (blk==0 && t < NH){
      float a = 0.f;
      for (int d=0; d<64; ++d) a += bk[t*HD+d]*Wa[64+d];
      bkdot[t] = a;
    }
  } else {
    int bs = blk - 144;                  // 0..4063
    int b = bs / SD, s = bs % SD;
    float wea = Wa[128 + lane];
    const float* row = desc + (size_t)bs * ND;
    #pragma unroll
    for (int hh=0; hh<3; ++hh){
      int h = wave + hh*4;
      float v = row[h*HD + lane] * wea;
      v = wredSum(v);
      if (lane==0) ei[(size_t)(b*NH + h)*NS + s] = v;
    }
  }
}

// N1: lk rows. 1024 blocks x 4 rows; uk in 36 regs/lane; 12 indep wredSums.
__global__ __launch_bounds__(256)
void lk_kernel(const float* __restrict__ nv, const float* __restrict__ uk,
               const float* __restrict__ bkdot, float* __restrict__ lk){
  __shared__ __align__(16) float S[4*ND];
  int blk = blockIdx.x, t = threadIdx.x, wave = t>>6, lane = t&63;
  float ukr[3][12], bkd[3];
  #pragma unroll
  for (int hh=0; hh<3; ++hh){
    int h = wave*3 + hh;
    bkd[hh] = bkdot[h];
    #pragma unroll
    for (int k=0;k<12;++k) ukr[hh][k] = uk[h*ND + lane + 64*k];
  }
  int j0 = blk*4;                        // 4 rows, same b (128 | 4)
  const float4* src = (const float4*)(nv + (size_t)j0*ND);
  ((float4*)S)[t]     = src[t];
  ((float4*)S)[t+256] = src[t+256];
  ((float4*)S)[t+512] = src[t+512];
  __syncthreads();
  float acc[12];
  #pragma unroll
  for (int rr=0; rr<4; ++rr){
    #pragma unroll
    for (int hh=0; hh<3; ++hh){
      float a = 0.f;
      #pragma unroll
      for (int k=0;k<12;++k) a += S[rr*ND + lane + 64*k]*ukr[hh][k];
      acc[rr*3+hh] = a;
    }
  }
  #pragma unroll
  for (int i=0;i<12;++i) acc[i] = wredSum(acc[i]);
  if (lane == 0){
    int b = j0 >> 7, jb = j0 & 127;
    #pragma unroll
    for (int rr=0; rr<4; ++rr)
      #pragma unroll
      for (int hh=0; hh<3; ++hh)
        lk[(size_t)(b*NH + wave*3 + hh)*NS + jb + rr] = acc[rr*3+hh] + bkd[hh];
  }
}

// N2: per (b,jg): all-24 softmax -> m partials (waves 0-2) + attn-tile rows
// [jg*16,jg*16+16) for all 12 heads (all waves; wave 3 starts immediately).
__global__ __launch_bounds__(256)
void msoft_attn(const float* __restrict__ nv, const float* __restrict__ lk,
                const float* __restrict__ ei, float* __restrict__ m_part,
                float* __restrict__ out){
  int blk = blockIdx.x;               // b*8 + jg
  int b = blk >> 3, jg = blk & 7;
  int t = threadIdx.x, wave = t >> 6, lane = t & 63;
  __shared__ float slk[NH*NS];
  __shared__ float sei[NH*NS];
  __shared__ float wf[24][NS];
  for (int i=t; i<NH*NS; i+=256) slk[i] = lk[(size_t)b*NH*NS + i];
  for (int i=t; i<NH*NS; i+=256) sei[i] = ei[(size_t)b*NH*NS + i];
  __syncthreads();
  #pragma unroll
  for (int rr=0; rr<6; ++rr){
    int r = wave*6 + rr;
    int h = r >> 1, which = r & 1;
    const float* eirow = (which==0) ? (sei + (h%6)*NS) : (sei + h*NS);
    float g = (which==0) ? 1.f : (h>=6 ? 1.f : 0.f);
    float x0 = (lane>=1) ? slk[h*NS+lane] + g*eirow[lane-1] : -3.0e38f;
    float x1 = slk[h*NS+lane+64] + g*eirow[lane+63];
    float mm = wredMax(fmaxf(x0,x1));
    float e0 = (lane>=1) ? __expf(x0-mm) : 0.f;  // col 0 masked -> exactly 0
    float e1 = __expf(x1-mm);
    float s  = wredSum(e0+e1);
    float inv = 1.f/s;
    wf[r][lane]    = e0*inv;
    wf[r][lane+64] = e1*inv;
  }
  __syncthreads();
  if (t < 192){                        // waves 0-2: m partials
    const float4* nvb = (const float4*)(nv + ((size_t)b*NS + jg*16)*ND);
    float4 acc[24];
    #pragma unroll
    for (int r=0;r<24;++r) acc[r] = make_float4(0.f,0.f,0.f,0.f);
    #pragma unroll 2
    for (int jj=0; jj<16; ++jj){
      float4 x = nvb[jj*192 + t];
      int j = jg*16 + jj;
      #pragma unroll
      for (int r=0;r<24;++r){
        float wr = wf[r][j];
        acc[r].x += wr*x.x; acc[r].y += wr*x.y;
        acc[r].z += wr*x.z; acc[r].w += wr*x.w;
      }
    }
    #pragma unroll
    for (int r=0;r<24;++r)
      ((float4*)(m_part + ((size_t)(b*24 + r)*8 + jg)*ND))[t] = acc[r];
  }
  // attn rows (wave 3 reaches here while waves 0-2 crunch m): 6144 float4
  float* abase = out + (size_t)NB*NS*ND + (size_t)(b*NH)*NS*NS;
  for (int idx=t; idx<6144; idx+=256){
    int h = idx >> 9;
    int rem = idx & 511;
    int il = rem >> 5, q = rem & 31;
    int i = jg*16 + il;
    const float* srcw = (i==0) ? wf[h*2] : wf[h*2+1];
    float4 v = { srcw[q*4], srcw[q*4+1], srcw[q*4+2], srcw[q*4+3] };
    ((float4*)(abase + (size_t)h*NS*NS))[i*32 + q] = v;
  }
}

// N3: per (b,h): sum 8 partials -> V-proj -> basis write (12.6 MB total)
__global__ __launch_bounds__(256)
void proj_basis(const float* __restrict__ m_part, const float* __restrict__ Wv,
                const float* __restrict__ bv, float* __restrict__ out){
  int bh = blockIdx.x;                // 0..383
  int b = bh / NH, h = bh % NH;
  int t = threadIdx.x, wave = t >> 6, lane = t & 63;
  __shared__ float msum0[ND], msum1[ND];
  __shared__ float cvec[2*HD];
  for (int i=t; i<2*ND; i+=256){
    int rl = (i >= ND);
    int c  = i - rl*ND;
    const float* mp = m_part + ((size_t)(b*24 + h*2 + rl)*8)*ND + c;
    float s = 0.f;
    #pragma unroll
    for (int g8=0; g8<8; ++g8) s += mp[(size_t)g8*ND];
    (rl ? msum1 : msum0)[c] = s;
  }
  __syncthreads();
  #pragma unroll
  for (int dd=0; dd<16; ++dd){
    int d = wave*16 + dd;
    const float* wvr = Wv + (size_t)(h*HD + d)*ND;
    float p0=0.f, p1=0.f;
    #pragma unroll
    for (int k=0; k<12; ++k){
      float wv = wvr[lane + 64*k];
      p0 += wv*msum0[lane + 64*k];
      p1 += wv*msum1[lane + 64*k];
    }
    p0 = wredSum(p0); p1 = wredSum(p1);
    if (lane==0){
      float bb = bv[h*HD + d];
      cvec[d]    = p0 + bb;
      cvec[64+d] = p1 + bb;
    }
  }
  __syncthreads();
  float* bo = out + (size_t)b*NS*ND + h*HD;
  #pragma unroll
  for (int k=0;k<8;++k){
    int idx = t + k*256;              // 2048 float4
    int i = idx>>4, q = idx&15;
    const float* srcc = (i==0) ? cvec : cvec+64;
    float4 v = { srcc[q*4], srcc[q*4+1], srcc[q*4+2], srcc[q*4+3] };
    *(float4*)(bo + (size_t)i*ND + q*4) = v;
  }
}

extern "C" void kernel_launch(void* const* d_in, const int* in_sizes, int n_in,
                              void* d_out, int out_size, void* d_ws, size_t ws_size,
                              hipStream_t stream) {
  const float* desc = (const float*)d_in[0];
  const float* nv   = (const float*)d_in[1];
  // d_in[2]=Wq, d_in[3]=bq: unused (softmax shift-invariance)
  const float* Wk   = (const float*)d_in[4];
  const float* bk   = (const float*)d_in[5];
  const float* Wv   = (const float*)d_in[6];
  const float* bv   = (const float*)d_in[7];
  const float* Wa   = (const float*)d_in[8];
  // d_in[9]=ba: unused (constant shift)
  float* out = (float*)d_out;
  float* ws  = (float*)d_ws;

  float* uk     = ws;               // 9216
  float* bkdot  = ws + 9216;        // 16
  float* eibuf  = ws + 9232;        // 49152
  float* lkbuf  = ws + 58384;       // 49152
  float* m_part = ws + 107536;      // 32*24*8*768 = 4718592

  fold_ei   <<<4208, 256, 0, stream>>>(Wk, bk, desc, Wa, uk, bkdot, eibuf);
  lk_kernel <<<1024, 256, 0, stream>>>(nv, uk, bkdot, lkbuf);
  msoft_attn<<<256,  256, 0, stream>>>(nv, lkbuf, eibuf, m_part, out);
  proj_basis<<<384,  256, 0, stream>>>(m_part, Wv, bv, out);
}